// Round 8
// baseline (465.703 us; speedup 1.0000x reference)
//
#include <hip/hip_runtime.h>
#include <hip/hip_bf16.h>

// ---------------------------------------------------------------------------
// 2-layer GAT (PyG GATConv semantics, eval mode, self-loops appended).
//   1) bucket_gemm1: heterogeneous grid — blocks <bblk bucket edges by dst>>8
//      (packed (src<<8)|local), last bucket block scans bucket totals;
//      blocks >=bblk run MFMA gemm1 tiles (x@W1 -> bf16 + a_s/a_d epilogue).
//   2) csr_bucket: per-256-node-bucket LDS hist+scan+place -> rowptr/srcs
//   3) agg1_fused: additive exp(v-8) softmax agg (8 lanes/edge, uint4 bf16
//      gathers) + bias + ELU + FUSED gemm2 (he@W2) + a_s2/a_d2 -> h2b
//   4) agg2: additive agg, 2 lanes/edge x 32 groups + fused log_softmax
// ---------------------------------------------------------------------------

#define NEG_SLOPE 0.2f
#define EPS_DEN 1e-16f
#define CSHIFT 8.0f          // shift-invariant softmax; |logit| <~ 9 here
#define BCAP 8192            // per-256-node-bucket capacity (mean ~4.4k)
#define ECHUNK 2048
#define G1_PITCH 136

typedef __attribute__((ext_vector_type(8))) short bf16x8;
typedef __attribute__((ext_vector_type(4))) float f32x4;

__device__ __forceinline__ float bf2f(unsigned short u) {
    return __uint_as_float(((unsigned)u) << 16);
}
__device__ __forceinline__ unsigned short f2bf(float f) {
    unsigned x = __float_as_uint(f);
    unsigned r = x + 0x7fffu + ((x >> 16) & 1u);
    return (unsigned short)(r >> 16);
}
__device__ __forceinline__ void bf2f2(unsigned u, float& lo, float& hi) {
    lo = __uint_as_float(u << 16);
    hi = __uint_as_float(u & 0xffff0000u);
}
// a[0..7] += p * bf16x8(h)
__device__ __forceinline__ void acc8(float* a, float p, uint4 h) {
    float f0, f1;
    bf2f2(h.x, f0, f1); a[0] = fmaf(p, f0, a[0]); a[1] = fmaf(p, f1, a[1]);
    bf2f2(h.y, f0, f1); a[2] = fmaf(p, f0, a[2]); a[3] = fmaf(p, f1, a[3]);
    bf2f2(h.z, f0, f1); a[4] = fmaf(p, f0, a[4]); a[5] = fmaf(p, f1, a[5]);
    bf2f2(h.w, f0, f1); a[6] = fmaf(p, f0, a[6]); a[7] = fmaf(p, f1, a[7]);
}

union __align__(16) SMem {
    struct { unsigned short As[64 * G1_PITCH]; unsigned short Cs[64 * 68]; } g;
    struct { int cnt[512]; int offs[512]; int flag; } b;
};

// ---------------- fused bucket + gemm1 ----------------

__global__ __launch_bounds__(256) void bucket_gemm1_kernel(
    const int* __restrict__ src, const int* __restrict__ dst,
    int* __restrict__ gcur, int* __restrict__ gbase, int* __restrict__ buf,
    int E, int nbuck, int bblk,
    const float* __restrict__ x, const float* __restrict__ W1,
    const float* __restrict__ att_s, const float* __restrict__ att_d,
    unsigned short* __restrict__ h1b, float* __restrict__ a_s,
    float* __restrict__ a_d, int N)
{
    __shared__ SMem sm;
    int tid = threadIdx.x;
    if ((int)blockIdx.x < bblk) {
        // ---------- bucket phase ----------
        int* cnt = sm.b.cnt; int* offs = sm.b.offs;
        for (int i = tid; i < nbuck; i += 256) cnt[i] = 0;
        __syncthreads();
        int base = blockIdx.x * ECHUNK;
        int lim = min(base + ECHUNK, E);
        int dl[8];
#pragma unroll
        for (int k = 0; k < 8; ++k) {
            int e = base + tid + 256 * k;
            dl[k] = (e < lim) ? dst[e] : -1;
        }
#pragma unroll
        for (int k = 0; k < 8; ++k)
            if (dl[k] >= 0) atomicAdd(&cnt[dl[k] >> 8], 1);
        __syncthreads();
        for (int i = tid; i < nbuck; i += 256) {
            offs[i] = atomicAdd(&gcur[i], cnt[i]);
            cnt[i] = 0;
        }
        __syncthreads();
#pragma unroll
        for (int k = 0; k < 8; ++k) {
            if (dl[k] >= 0) {
                int e = base + tid + 256 * k;
                int b = dl[k] >> 8;
                int idx = offs[b] + atomicAdd(&cnt[b], 1);
                if (idx < BCAP)
                    buf[(size_t)b * BCAP + idx] = (src[e] << 8) | (dl[k] & 255);
            }
        }
        // last-block ticket -> scan bucket totals into gbase
        __threadfence();
        __syncthreads();
        if (tid == 0) sm.b.flag = (atomicAdd(&gcur[nbuck], 1) == bblk - 1) ? 1 : 0;
        __syncthreads();
        if (sm.b.flag && tid < 64) {
            int lane = tid, carry = 0;
            for (int bs = 0; bs < nbuck; bs += 64) {
                int i = bs + lane;
                int v = (i < nbuck) ? atomicAdd(&gcur[i], 0) : 0;
                int sc = v;
#pragma unroll
                for (int off = 1; off < 64; off <<= 1) {
                    int o = __shfl_up(sc, off);
                    if (lane >= off) sc += o;
                }
                if (i < nbuck) gbase[i] = carry + sc - v;
                carry += __shfl(sc, 63);
            }
        }
    } else {
        // ---------- gemm1 MFMA tile ----------
        unsigned short* As = sm.g.As;
        unsigned short* Cs = sm.g.Cs;
        int bb = blockIdx.x - bblk;
        int lane = tid & 63, wv = tid >> 6;
        int quad = lane >> 4, l16 = lane & 15;
        bf16x8 Bf[4][4];
#pragma unroll
        for (int ks = 0; ks < 4; ++ks)
#pragma unroll
            for (int nt = 0; nt < 4; ++nt) {
                bf16x8 f;
#pragma unroll
                for (int j = 0; j < 8; ++j)
                    f[j] = (short)f2bf(W1[(ks * 32 + quad * 8 + j) * 64 + nt * 16 + l16]);
                Bf[ks][nt] = f;
            }
        float asw[4], adw[4];
#pragma unroll
        for (int nt = 0; nt < 4; ++nt) {
            asw[nt] = att_s[nt * 16 + l16];
            adw[nt] = att_d[nt * 16 + l16];
        }
        int row0 = bb << 6;
#pragma unroll
        for (int i = 0; i < 8; ++i) {
            int idx = tid + 256 * i;
            int r = idx >> 5, c4 = idx & 31;
            int row = row0 + r;
            float4 v = (row < N) ? ((const float4*)x)[(size_t)row * 32 + c4]
                                 : make_float4(0.f, 0.f, 0.f, 0.f);
            ushort4 u;
            u.x = f2bf(v.x); u.y = f2bf(v.y); u.z = f2bf(v.z); u.w = f2bf(v.w);
            *(ushort4*)&As[r * G1_PITCH + c4 * 4] = u;
        }
        __syncthreads();
        f32x4 acc[4];
#pragma unroll
        for (int nt = 0; nt < 4; ++nt) acc[nt] = (f32x4){0.f, 0.f, 0.f, 0.f};
#pragma unroll
        for (int ks = 0; ks < 4; ++ks) {
            bf16x8 Af = *(const bf16x8*)&As[(wv * 16 + l16) * G1_PITCH + ks * 32 + quad * 8];
#pragma unroll
            for (int nt = 0; nt < 4; ++nt)
                acc[nt] = __builtin_amdgcn_mfma_f32_16x16x32_bf16(Af, Bf[ks][nt], acc[nt], 0, 0, 0);
        }
        int lrow = wv * 16 + quad * 4;
#pragma unroll
        for (int nt = 0; nt < 4; ++nt) {
            float ps[4], pd[4];
#pragma unroll
            for (int r = 0; r < 4; ++r) {
                ps[r] = acc[nt][r] * asw[nt];
                pd[r] = acc[nt][r] * adw[nt];
            }
#pragma unroll
            for (int off = 1; off < 8; off <<= 1)
#pragma unroll
                for (int r = 0; r < 4; ++r) {
                    ps[r] += __shfl_xor(ps[r], off);
                    pd[r] += __shfl_xor(pd[r], off);
                }
            if ((l16 & 7) == 0) {
                int head = nt * 2 + (l16 >> 3);
#pragma unroll
                for (int r = 0; r < 4; ++r) {
                    int row = row0 + lrow + r;
                    if (row < N) {
                        a_s[row * 8 + head] = ps[r];
                        a_d[row * 8 + head] = pd[r];
                    }
                }
            }
        }
#pragma unroll
        for (int nt = 0; nt < 4; ++nt)
#pragma unroll
            for (int r = 0; r < 4; ++r)
                Cs[(lrow + r) * 68 + nt * 16 + l16] = f2bf(acc[nt][r]);
        __syncthreads();
#pragma unroll
        for (int i = 0; i < 4; ++i) {
            int idx = tid + 256 * i;
            int r = idx >> 4, c4 = idx & 15;
            int row = row0 + r;
            if (row < N) {
                ushort4 u = *(const ushort4*)&Cs[r * 68 + c4 * 4];
                ((ushort4*)h1b)[(size_t)row * 16 + c4] = u;
            }
        }
    }
}

// ---------------- csr_bucket: 256-node buckets, hist+scan+place --------------

__global__ __launch_bounds__(256) void csr_bucket_kernel(
    const int* __restrict__ gcur, const int* __restrict__ gbase,
    const int* __restrict__ buf, int* __restrict__ rowptr,
    int* __restrict__ srcs, int N, int E)
{
    __shared__ int cnt[256];
    __shared__ int wsum[4];
    __shared__ int wbase[4];
    int b = blockIdx.x, tid = threadIdx.x;
    int lane = tid & 63, wv = tid >> 6;
    cnt[tid] = 0;
    __syncthreads();
    int n = min(gcur[b], BCAP);
    const int* p = buf + (size_t)b * BCAP;
    for (int i = tid; i < n; i += 256) atomicAdd(&cnt[p[i] & 255], 1);
    __syncthreads();
    int c = cnt[tid];
    int sc = c;
#pragma unroll
    for (int off = 1; off < 64; off <<= 1) {
        int o = __shfl_up(sc, off);
        if (lane >= off) sc += o;
    }
    if (lane == 63) wsum[wv] = sc;
    __syncthreads();
    if (tid == 0) {
        int acc = 0;
#pragma unroll
        for (int k = 0; k < 4; ++k) { wbase[k] = acc; acc += wsum[k]; }
    }
    __syncthreads();
    int excl = gbase[b] + wbase[wv] + (sc - c);
    int node = (b << 8) + tid;
    if (node < N) rowptr[node] = excl;
    cnt[tid] = excl;                    // reuse as placement cursor
    __syncthreads();
    for (int i = tid; i < n; i += 256) {
        int v = p[i];
        int posi = atomicAdd(&cnt[v & 255], 1);
        srcs[posi] = v >> 8;
    }
    if (b == 0 && tid == 0) rowptr[N] = E;
}

// ---------------- agg1 fused: softmax agg + ELU + gemm2 + a_s2/a_d2 ----------
// g=lane>>3 edge-group, pos=lane&7 = head; 8 channels (uint4 bf16) per lane.

__global__ __launch_bounds__(256) void agg1_fused_kernel(
    const unsigned short* __restrict__ h1b, const float* __restrict__ a_s,
    const float* __restrict__ a_d, const int* __restrict__ rowptr,
    const int* __restrict__ srcs, const float* __restrict__ b1,
    const float* __restrict__ W2, const float* __restrict__ att_s2,
    const float* __restrict__ att_d2, unsigned short* __restrict__ h2b,
    float* __restrict__ a_s2, float* __restrict__ a_d2, int N)
{
    int lane = threadIdx.x & 63, wid = threadIdx.x >> 6;
    int node = blockIdx.x * 4 + wid;
    if (node >= N) return;
    int g = lane >> 3, pos = lane & 7;
    int beg = rowptr[node], end = rowptr[node + 1];
    float adn = a_d[node * 8 + pos];
    const uint4* h1v = (const uint4*)h1b;        // 8 uint4 per 64-ch row

    float l = 0.f, a[8] = {0.f, 0.f, 0.f, 0.f, 0.f, 0.f, 0.f, 0.f};
    if (g == 0) {                                // self-loop in group 0
        float v = a_s[node * 8 + pos] + adn;
        v = fmaxf(v, NEG_SLOPE * v);
        float p = __expf(v - CSHIFT);
        l = p;
        acc8(a, p, h1v[(size_t)node * 8 + pos]);
    }
    int e = beg + g;
    for (; e + 8 < end; e += 16) {               // 2-deep, 16 edges in flight
        int s0 = srcs[e], s1 = srcs[e + 8];
        float va0 = a_s[s0 * 8 + pos], va1 = a_s[s1 * 8 + pos];
        uint4 h0 = h1v[(size_t)s0 * 8 + pos];
        uint4 h1_ = h1v[(size_t)s1 * 8 + pos];
        float v0 = va0 + adn; v0 = fmaxf(v0, NEG_SLOPE * v0);
        float v1 = va1 + adn; v1 = fmaxf(v1, NEG_SLOPE * v1);
        float p0 = __expf(v0 - CSHIFT), p1 = __expf(v1 - CSHIFT);
        l += p0 + p1;
        acc8(a, p0, h0);
        acc8(a, p1, h1_);
    }
    if (e < end) {
        int s = srcs[e];
        float va = a_s[s * 8 + pos];
        uint4 h = h1v[(size_t)s * 8 + pos];
        float v = va + adn; v = fmaxf(v, NEG_SLOPE * v);
        float p = __expf(v - CSHIFT);
        l += p;
        acc8(a, p, h);
    }
    // merge the 8 groups (plain sums; lane bits 3..5)
#pragma unroll
    for (int off = 8; off < 64; off <<= 1) {
        l += __shfl_xor(l, off);
#pragma unroll
        for (int j = 0; j < 8; ++j) a[j] += __shfl_xor(a[j], off);
    }
    float inv = 1.f / (l + EPS_DEN);
    float4 bb0 = ((const float4*)b1)[pos * 2];
    float4 bb1 = ((const float4*)b1)[pos * 2 + 1];
    float o[8];
    o[0] = fmaf(a[0], inv, bb0.x); o[1] = fmaf(a[1], inv, bb0.y);
    o[2] = fmaf(a[2], inv, bb0.z); o[3] = fmaf(a[3], inv, bb0.w);
    o[4] = fmaf(a[4], inv, bb1.x); o[5] = fmaf(a[5], inv, bb1.y);
    o[6] = fmaf(a[6], inv, bb1.z); o[7] = fmaf(a[7], inv, bb1.w);
#pragma unroll
    for (int j = 0; j < 8; ++j)
        o[j] = o[j] > 0.f ? o[j] : __expf(o[j]) - 1.f;   // ELU -> he (regs)

    // fused gemm2: group g computes classes 2g, 2g+1
    float r0 = 0.f, r1 = 0.f;
#pragma unroll
    for (int j = 0; j < 8; ++j) {
        float2 w = ((const float2*)W2)[(8 * pos + j) * 8 + g];
        r0 = fmaf(o[j], w.x, r0);
        r1 = fmaf(o[j], w.y, r1);
    }
    // sum over k (pos dimension: lane bits 0..2)
    r0 += __shfl_xor(r0, 1); r1 += __shfl_xor(r1, 1);
    r0 += __shfl_xor(r0, 2); r1 += __shfl_xor(r1, 2);
    r0 += __shfl_xor(r0, 4); r1 += __shfl_xor(r1, 4);
    // a_s2/a_d2 = sum_c h2[c]*att2[c] (partials per group, reduce over g)
    float2 ws = ((const float2*)att_s2)[g];
    float2 wd = ((const float2*)att_d2)[g];
    float ps = r0 * ws.x + r1 * ws.y;
    float pd = r0 * wd.x + r1 * wd.y;
    ps += __shfl_xor(ps, 8);  pd += __shfl_xor(pd, 8);
    ps += __shfl_xor(ps, 16); pd += __shfl_xor(pd, 16);
    ps += __shfl_xor(ps, 32); pd += __shfl_xor(pd, 32);
    if (pos == 0) {
        ushort2 u; u.x = f2bf(r0); u.y = f2bf(r1);
        ((ushort2*)h2b)[(size_t)node * 8 + g] = u;
    }
    if (lane == 0) { a_s2[node] = ps; a_d2[node] = pd; }
}

// ---------------- agg2: 2 lanes/edge x 32 groups + fused log_softmax ---------

__global__ __launch_bounds__(256) void agg2_kernel(
    const unsigned short* __restrict__ h2b, const float* __restrict__ a_s2,
    const float* __restrict__ a_d2, const int* __restrict__ rowptr,
    const int* __restrict__ srcs, const float* __restrict__ b2,
    float* __restrict__ out, int N)
{
    int lane = threadIdx.x & 63, wid = threadIdx.x >> 6;
    int node = blockIdx.x * 4 + wid;
    if (node >= N) return;
    int g = lane >> 1, pos = lane & 1;
    int beg = rowptr[node], end = rowptr[node + 1];
    float adn = a_d2[node];
    const uint4* h2v = (const uint4*)h2b;        // 2 uint4 per 16-ch row

    float l = 0.f, a[8] = {0.f, 0.f, 0.f, 0.f, 0.f, 0.f, 0.f, 0.f};
    if (g == 0) {                                // self-loop in group 0
        float v = a_s2[node] + adn;
        v = fmaxf(v, NEG_SLOPE * v);
        float p = __expf(v - CSHIFT);
        l = p;
        acc8(a, p, h2v[(size_t)node * 2 + pos]);
    }
    for (int e = beg + g; e < end; e += 32) {    // 32 edges in flight
        int s = srcs[e];
        float va = a_s2[s];
        uint4 h = h2v[(size_t)s * 2 + pos];
        float v = va + adn; v = fmaxf(v, NEG_SLOPE * v);
        float p = __expf(v - CSHIFT);
        l += p;
        acc8(a, p, h);
    }
    // merge the 32 groups (lane bits 1..5)
#pragma unroll
    for (int off = 2; off < 64; off <<= 1) {
        l += __shfl_xor(l, off);
#pragma unroll
        for (int j = 0; j < 8; ++j) a[j] += __shfl_xor(a[j], off);
    }
    float inv = 1.f / (l + EPS_DEN);
    float4 bb0 = ((const float4*)b2)[pos * 2];
    float4 bb1 = ((const float4*)b2)[pos * 2 + 1];
    float o[8];
    o[0] = fmaf(a[0], inv, bb0.x); o[1] = fmaf(a[1], inv, bb0.y);
    o[2] = fmaf(a[2], inv, bb0.z); o[3] = fmaf(a[3], inv, bb0.w);
    o[4] = fmaf(a[4], inv, bb1.x); o[5] = fmaf(a[5], inv, bb1.y);
    o[6] = fmaf(a[6], inv, bb1.z); o[7] = fmaf(a[7], inv, bb1.w);
    // log_softmax over 16 classes (8 per lane + pair lane via xor 1)
    float mx = o[0];
#pragma unroll
    for (int j = 1; j < 8; ++j) mx = fmaxf(mx, o[j]);
    mx = fmaxf(mx, __shfl_xor(mx, 1));
    float se = 0.f;
#pragma unroll
    for (int j = 0; j < 8; ++j) se += __expf(o[j] - mx);
    se += __shfl_xor(se, 1);
    float ls = mx + logf(se);
    if (g == 0) {
        ((float4*)out)[(size_t)node * 4 + pos * 2] =
            make_float4(o[0] - ls, o[1] - ls, o[2] - ls, o[3] - ls);
        ((float4*)out)[(size_t)node * 4 + pos * 2 + 1] =
            make_float4(o[4] - ls, o[5] - ls, o[6] - ls, o[7] - ls);
    }
}

// ---------------------------------------------------------------------------

extern "C" void kernel_launch(void* const* d_in, const int* in_sizes, int n_in,
                              void* d_out, int out_size, void* d_ws, size_t ws_size,
                              hipStream_t stream) {
    const float* x    = (const float*)d_in[0];
    const int*   ei   = (const int*)d_in[1];
    const float* W1   = (const float*)d_in[2];
    const float* b1   = (const float*)d_in[3];
    const float* as1  = (const float*)d_in[4];
    const float* ad1  = (const float*)d_in[5];
    const float* W2   = (const float*)d_in[6];
    const float* b2   = (const float*)d_in[7];
    const float* as2  = (const float*)d_in[8];
    const float* ad2  = (const float*)d_in[9];
    float* out = (float*)d_out;

    int N = in_sizes[0] / 128;
    int E = in_sizes[1] / 2;
    const int* srcp = ei;
    const int* dstp = ei + E;
    int nbuck = (N + 255) >> 8;               // 391 for N=100k

    char* w = (char*)d_ws;
    auto alloc = [&](size_t bytes) {
        void* p = (void*)w;
        w += (bytes + 255) & ~(size_t)255;
        return p;
    };
    unsigned short* h1b = (unsigned short*)alloc((size_t)N * 64 * 2);
    float* a_s1  = (float*)alloc((size_t)N * 8 * 4);
    float* a_d1  = (float*)alloc((size_t)N * 8 * 4);
    unsigned short* h2b = (unsigned short*)alloc((size_t)N * 16 * 2);
    float* a_s2b = (float*)alloc((size_t)N * 4);
    float* a_d2b = (float*)alloc((size_t)N * 4);
    int*   rowp  = (int*)alloc((size_t)(N + 1) * 4);
    int*   srcs  = (int*)alloc((size_t)E * 4);
    int*   gcur  = (int*)alloc((size_t)(nbuck + 1) * 4);   // +1 = done ticket
    int*   gbase = (int*)alloc((size_t)nbuck * 4);
    int*   buf   = (int*)alloc((size_t)nbuck * BCAP * 4);  // 12.8 MB

    hipMemsetAsync(gcur, 0, (size_t)(nbuck + 1) * 4, stream);

    int bblk = (E + ECHUNK - 1) / ECHUNK;     // 782
    int g1blocks = (N + 63) >> 6;             // 1563
    bucket_gemm1_kernel<<<bblk + g1blocks, 256, 0, stream>>>(
        srcp, dstp, gcur, gbase, buf, E, nbuck, bblk,
        x, W1, as1, ad1, h1b, a_s1, a_d1, N);
    csr_bucket_kernel<<<nbuck, 256, 0, stream>>>(gcur, gbase, buf, rowp, srcs, N, E);
    agg1_fused_kernel<<<(N + 3) / 4, 256, 0, stream>>>(
        h1b, a_s1, a_d1, rowp, srcs, b1, W2, as2, ad2, h2b, a_s2b, a_d2b, N);
    agg2_kernel<<<(N + 3) / 4, 256, 0, stream>>>(h2b, a_s2b, a_d2b, rowp, srcs, b2, out, N);
}

// Round 9
// 356.147 us; speedup vs baseline: 1.3076x; 1.3076x over previous
//
#include <hip/hip_runtime.h>
#include <hip/hip_bf16.h>

// ---------------------------------------------------------------------------
// 2-layer GAT (PyG GATConv semantics, eval mode, self-loops appended).
//   1) bucket (dst>>9, 196 buckets) -> gscan -> csr_bucket (512-node):
//      CSR build, separate kernels (R8 post-mortem: do NOT fuse the
//      scatter/atomic personality with the MFMA personality in one grid)
//   2) gemm1 (MFMA 16x16x32 bf16): h1 = x @ W1 -> bf16 + a_s/a_d epilogue
//   3) agg1_fused: additive exp(v-8) softmax agg (8 lanes/edge, uint4 bf16
//      gathers) + bias + ELU + fused gemm2 (he@W2) + a_s2/a_d2 -> h2b
//   4) agg2: additive agg, 2 lanes/edge x 32 groups + fused log_softmax
// ---------------------------------------------------------------------------

#define NEG_SLOPE 0.2f
#define EPS_DEN 1e-16f
#define CSHIFT 8.0f          // shift-invariant softmax; |logit| <~ 9 here
#define NBUCK_MAX 256
#define BCAP 16384           // per-512-node-bucket capacity (mean ~8.7k)
#define ECHUNK 2048
#define G1_PITCH 136

typedef __attribute__((ext_vector_type(8))) short bf16x8;
typedef __attribute__((ext_vector_type(4))) float f32x4;

__device__ __forceinline__ float bf2f(unsigned short u) {
    return __uint_as_float(((unsigned)u) << 16);
}
__device__ __forceinline__ unsigned short f2bf(float f) {
    unsigned x = __float_as_uint(f);
    unsigned r = x + 0x7fffu + ((x >> 16) & 1u);
    return (unsigned short)(r >> 16);
}
__device__ __forceinline__ void bf2f2(unsigned u, float& lo, float& hi) {
    lo = __uint_as_float(u << 16);
    hi = __uint_as_float(u & 0xffff0000u);
}
// a[0..7] += p * bf16x8(h)
__device__ __forceinline__ void acc8(float* a, float p, uint4 h) {
    float f0, f1;
    bf2f2(h.x, f0, f1); a[0] = fmaf(p, f0, a[0]); a[1] = fmaf(p, f1, a[1]);
    bf2f2(h.y, f0, f1); a[2] = fmaf(p, f0, a[2]); a[3] = fmaf(p, f1, a[3]);
    bf2f2(h.z, f0, f1); a[4] = fmaf(p, f0, a[4]); a[5] = fmaf(p, f1, a[5]);
    bf2f2(h.w, f0, f1); a[6] = fmaf(p, f0, a[6]); a[7] = fmaf(p, f1, a[7]);
}

// ---------------- CSR build (separate kernels — R7 structure) ----------------

__global__ __launch_bounds__(256) void bucket_kernel(
    const int* __restrict__ src, const int* __restrict__ dst,
    int* __restrict__ gcur, int* __restrict__ buf, int E, int nbuck)
{
    __shared__ int cnt[NBUCK_MAX];
    __shared__ int offs[NBUCK_MAX];
    int tid = threadIdx.x;
    for (int i = tid; i < nbuck; i += 256) cnt[i] = 0;
    __syncthreads();
    int base = blockIdx.x * ECHUNK;
    int lim = min(base + ECHUNK, E);
    for (int e = base + tid; e < lim; e += 256)
        atomicAdd(&cnt[dst[e] >> 9], 1);
    __syncthreads();
    for (int i = tid; i < nbuck; i += 256) {
        offs[i] = atomicAdd(&gcur[i], cnt[i]);
        cnt[i] = 0;
    }
    __syncthreads();
    for (int e = base + tid; e < lim; e += 256) {
        int d = dst[e];
        int b = d >> 9;
        int idx = offs[b] + atomicAdd(&cnt[b], 1);
        if (idx < BCAP)
            buf[(size_t)b * BCAP + idx] = (src[e] << 9) | (d & 511);
    }
}

__global__ void gscan_kernel(const int* __restrict__ gcur, int* __restrict__ gbase, int B) {
    int lane = threadIdx.x;
    int carry = 0;
    for (int base = 0; base < B; base += 64) {
        int i = base + lane;
        int v = (i < B) ? gcur[i] : 0;
        int sc = v;
#pragma unroll
        for (int off = 1; off < 64; off <<= 1) {
            int o = __shfl_up(sc, off);
            if (lane >= off) sc += o;
        }
        if (i < B) gbase[i] = carry + sc - v;
        carry += __shfl(sc, 63);
    }
}

__global__ __launch_bounds__(256) void csr_bucket_kernel(
    const int* __restrict__ gcur, const int* __restrict__ gbase,
    const int* __restrict__ buf, int* __restrict__ rowptr,
    int* __restrict__ srcs, int N, int E)
{
    __shared__ int cnt[512];
    __shared__ int wsum[4];
    __shared__ int wbase[4];
    int b = blockIdx.x, tid = threadIdx.x;
    int lane = tid & 63, wv = tid >> 6;
    cnt[2 * tid] = 0; cnt[2 * tid + 1] = 0;
    __syncthreads();
    int n = min(gcur[b], BCAP);
    const int* p = buf + (size_t)b * BCAP;
    for (int i = tid; i < n; i += 256) atomicAdd(&cnt[p[i] & 511], 1);
    __syncthreads();
    int c0 = cnt[2 * tid], c1 = cnt[2 * tid + 1];
    int s = c0 + c1;
    int sc = s;
#pragma unroll
    for (int off = 1; off < 64; off <<= 1) {
        int o = __shfl_up(sc, off);
        if (lane >= off) sc += o;
    }
    if (lane == 63) wsum[wv] = sc;
    __syncthreads();
    if (tid == 0) {
        int acc = 0;
#pragma unroll
        for (int k = 0; k < 4; ++k) { wbase[k] = acc; acc += wsum[k]; }
    }
    __syncthreads();
    int base = gbase[b];
    int g0 = base + wbase[wv] + (sc - s);
    int g1 = g0 + c0;
    int node0 = (b << 9) + 2 * tid;
    if (node0 < N)     rowptr[node0]     = g0;
    if (node0 + 1 < N) rowptr[node0 + 1] = g1;
    cnt[2 * tid] = g0; cnt[2 * tid + 1] = g1;   // reuse as placement cursors
    __syncthreads();
    for (int i = tid; i < n; i += 256) {
        int v = p[i];
        int posi = atomicAdd(&cnt[v & 511], 1);
        srcs[posi] = v >> 9;
    }
    if (b == 0 && tid == 0) rowptr[N] = E;
}

// ---------------- GEMM1 (MFMA): [N,128] @ [128,64] -> bf16 -------------------

__global__ __launch_bounds__(256) void gemm1_mfma_kernel(
    const float* __restrict__ x, const float* __restrict__ W1,
    const float* __restrict__ att_s, const float* __restrict__ att_d,
    unsigned short* __restrict__ h1b, float* __restrict__ a_s,
    float* __restrict__ a_d, int N)
{
    __shared__ unsigned short As[64 * G1_PITCH];
    __shared__ unsigned short Cs[64 * 68];
    int tid = threadIdx.x;
    int lane = tid & 63, wv = tid >> 6;
    int quad = lane >> 4, l16 = lane & 15;

    bf16x8 Bf[4][4];
#pragma unroll
    for (int ks = 0; ks < 4; ++ks)
#pragma unroll
        for (int nt = 0; nt < 4; ++nt) {
            bf16x8 f;
#pragma unroll
            for (int j = 0; j < 8; ++j)
                f[j] = (short)f2bf(W1[(ks * 32 + quad * 8 + j) * 64 + nt * 16 + l16]);
            Bf[ks][nt] = f;
        }
    float asw[4], adw[4];
#pragma unroll
    for (int nt = 0; nt < 4; ++nt) {
        asw[nt] = att_s[nt * 16 + l16];
        adw[nt] = att_d[nt * 16 + l16];
    }

    int nblocks = (N + 63) >> 6;
    for (int blk = blockIdx.x; blk < nblocks; blk += gridDim.x) {
        int row0 = blk << 6;
        __syncthreads();
#pragma unroll
        for (int i = 0; i < 8; ++i) {
            int idx = tid + 256 * i;
            int r = idx >> 5, c4 = idx & 31;
            int row = row0 + r;
            float4 v = (row < N) ? ((const float4*)x)[(size_t)row * 32 + c4]
                                 : make_float4(0.f, 0.f, 0.f, 0.f);
            ushort4 u;
            u.x = f2bf(v.x); u.y = f2bf(v.y); u.z = f2bf(v.z); u.w = f2bf(v.w);
            *(ushort4*)&As[r * G1_PITCH + c4 * 4] = u;
        }
        __syncthreads();
        f32x4 acc[4];
#pragma unroll
        for (int nt = 0; nt < 4; ++nt) acc[nt] = (f32x4){0.f, 0.f, 0.f, 0.f};
#pragma unroll
        for (int ks = 0; ks < 4; ++ks) {
            bf16x8 Af = *(const bf16x8*)&As[(wv * 16 + l16) * G1_PITCH + ks * 32 + quad * 8];
#pragma unroll
            for (int nt = 0; nt < 4; ++nt)
                acc[nt] = __builtin_amdgcn_mfma_f32_16x16x32_bf16(Af, Bf[ks][nt], acc[nt], 0, 0, 0);
        }
        int lrow = wv * 16 + quad * 4;
#pragma unroll
        for (int nt = 0; nt < 4; ++nt) {
            float ps[4], pd[4];
#pragma unroll
            for (int r = 0; r < 4; ++r) {
                ps[r] = acc[nt][r] * asw[nt];
                pd[r] = acc[nt][r] * adw[nt];
            }
#pragma unroll
            for (int off = 1; off < 8; off <<= 1)
#pragma unroll
                for (int r = 0; r < 4; ++r) {
                    ps[r] += __shfl_xor(ps[r], off);
                    pd[r] += __shfl_xor(pd[r], off);
                }
            if ((l16 & 7) == 0) {
                int head = nt * 2 + (l16 >> 3);
#pragma unroll
                for (int r = 0; r < 4; ++r) {
                    int row = row0 + lrow + r;
                    if (row < N) {
                        a_s[row * 8 + head] = ps[r];
                        a_d[row * 8 + head] = pd[r];
                    }
                }
            }
        }
#pragma unroll
        for (int nt = 0; nt < 4; ++nt)
#pragma unroll
            for (int r = 0; r < 4; ++r)
                Cs[(lrow + r) * 68 + nt * 16 + l16] = f2bf(acc[nt][r]);
        __syncthreads();
#pragma unroll
        for (int i = 0; i < 4; ++i) {
            int idx = tid + 256 * i;
            int r = idx >> 4, c4 = idx & 15;
            int row = row0 + r;
            if (row < N) {
                ushort4 u = *(const ushort4*)&Cs[r * 68 + c4 * 4];
                ((ushort4*)h1b)[(size_t)row * 16 + c4] = u;
            }
        }
    }
}

// ---------------- agg1 fused: softmax agg + ELU + gemm2 + a_s2/a_d2 ----------
// g=lane>>3 edge-group, pos=lane&7 = head; 8 channels (uint4 bf16) per lane.

__global__ __launch_bounds__(256) void agg1_fused_kernel(
    const unsigned short* __restrict__ h1b, const float* __restrict__ a_s,
    const float* __restrict__ a_d, const int* __restrict__ rowptr,
    const int* __restrict__ srcs, const float* __restrict__ b1,
    const float* __restrict__ W2, const float* __restrict__ att_s2,
    const float* __restrict__ att_d2, unsigned short* __restrict__ h2b,
    float* __restrict__ a_s2, float* __restrict__ a_d2, int N)
{
    int lane = threadIdx.x & 63, wid = threadIdx.x >> 6;
    int node = blockIdx.x * 4 + wid;
    if (node >= N) return;
    int g = lane >> 3, pos = lane & 7;
    int beg = rowptr[node], end = rowptr[node + 1];
    float adn = a_d[node * 8 + pos];
    const uint4* h1v = (const uint4*)h1b;        // 8 uint4 per 64-ch row

    float l = 0.f, a[8] = {0.f, 0.f, 0.f, 0.f, 0.f, 0.f, 0.f, 0.f};
    if (g == 0) {                                // self-loop in group 0
        float v = a_s[node * 8 + pos] + adn;
        v = fmaxf(v, NEG_SLOPE * v);
        float p = __expf(v - CSHIFT);
        l = p;
        acc8(a, p, h1v[(size_t)node * 8 + pos]);
    }
    int e = beg + g;
    for (; e + 8 < end; e += 16) {               // 2-deep, 16 edges in flight
        int s0 = srcs[e], s1 = srcs[e + 8];
        float va0 = a_s[s0 * 8 + pos], va1 = a_s[s1 * 8 + pos];
        uint4 h0 = h1v[(size_t)s0 * 8 + pos];
        uint4 h1_ = h1v[(size_t)s1 * 8 + pos];
        float v0 = va0 + adn; v0 = fmaxf(v0, NEG_SLOPE * v0);
        float v1 = va1 + adn; v1 = fmaxf(v1, NEG_SLOPE * v1);
        float p0 = __expf(v0 - CSHIFT), p1 = __expf(v1 - CSHIFT);
        l += p0 + p1;
        acc8(a, p0, h0);
        acc8(a, p1, h1_);
    }
    if (e < end) {
        int s = srcs[e];
        float va = a_s[s * 8 + pos];
        uint4 h = h1v[(size_t)s * 8 + pos];
        float v = va + adn; v = fmaxf(v, NEG_SLOPE * v);
        float p = __expf(v - CSHIFT);
        l += p;
        acc8(a, p, h);
    }
    // merge the 8 groups (plain sums; lane bits 3..5)
#pragma unroll
    for (int off = 8; off < 64; off <<= 1) {
        l += __shfl_xor(l, off);
#pragma unroll
        for (int j = 0; j < 8; ++j) a[j] += __shfl_xor(a[j], off);
    }
    float inv = 1.f / (l + EPS_DEN);
    float4 bb0 = ((const float4*)b1)[pos * 2];
    float4 bb1 = ((const float4*)b1)[pos * 2 + 1];
    float o[8];
    o[0] = fmaf(a[0], inv, bb0.x); o[1] = fmaf(a[1], inv, bb0.y);
    o[2] = fmaf(a[2], inv, bb0.z); o[3] = fmaf(a[3], inv, bb0.w);
    o[4] = fmaf(a[4], inv, bb1.x); o[5] = fmaf(a[5], inv, bb1.y);
    o[6] = fmaf(a[6], inv, bb1.z); o[7] = fmaf(a[7], inv, bb1.w);
#pragma unroll
    for (int j = 0; j < 8; ++j)
        o[j] = o[j] > 0.f ? o[j] : __expf(o[j]) - 1.f;   // ELU -> he (regs)

    // fused gemm2: group g computes classes 2g, 2g+1
    float r0 = 0.f, r1 = 0.f;
#pragma unroll
    for (int j = 0; j < 8; ++j) {
        float2 w = ((const float2*)W2)[(8 * pos + j) * 8 + g];
        r0 = fmaf(o[j], w.x, r0);
        r1 = fmaf(o[j], w.y, r1);
    }
    // sum over k (pos dimension: lane bits 0..2)
    r0 += __shfl_xor(r0, 1); r1 += __shfl_xor(r1, 1);
    r0 += __shfl_xor(r0, 2); r1 += __shfl_xor(r1, 2);
    r0 += __shfl_xor(r0, 4); r1 += __shfl_xor(r1, 4);
    // a_s2/a_d2 = sum_c h2[c]*att2[c] (partials per group, reduce over g)
    float2 ws = ((const float2*)att_s2)[g];
    float2 wd = ((const float2*)att_d2)[g];
    float ps = r0 * ws.x + r1 * ws.y;
    float pd = r0 * wd.x + r1 * wd.y;
    ps += __shfl_xor(ps, 8);  pd += __shfl_xor(pd, 8);
    ps += __shfl_xor(ps, 16); pd += __shfl_xor(pd, 16);
    ps += __shfl_xor(ps, 32); pd += __shfl_xor(pd, 32);
    if (pos == 0) {
        ushort2 u; u.x = f2bf(r0); u.y = f2bf(r1);
        ((ushort2*)h2b)[(size_t)node * 8 + g] = u;
    }
    if (lane == 0) { a_s2[node] = ps; a_d2[node] = pd; }
}

// ---------------- agg2: 2 lanes/edge x 32 groups + fused log_softmax ---------

__global__ __launch_bounds__(256) void agg2_kernel(
    const unsigned short* __restrict__ h2b, const float* __restrict__ a_s2,
    const float* __restrict__ a_d2, const int* __restrict__ rowptr,
    const int* __restrict__ srcs, const float* __restrict__ b2,
    float* __restrict__ out, int N)
{
    int lane = threadIdx.x & 63, wid = threadIdx.x >> 6;
    int node = blockIdx.x * 4 + wid;
    if (node >= N) return;
    int g = lane >> 1, pos = lane & 1;
    int beg = rowptr[node], end = rowptr[node + 1];
    float adn = a_d2[node];
    const uint4* h2v = (const uint4*)h2b;        // 2 uint4 per 16-ch row

    float l = 0.f, a[8] = {0.f, 0.f, 0.f, 0.f, 0.f, 0.f, 0.f, 0.f};
    if (g == 0) {                                // self-loop in group 0
        float v = a_s2[node] + adn;
        v = fmaxf(v, NEG_SLOPE * v);
        float p = __expf(v - CSHIFT);
        l = p;
        acc8(a, p, h2v[(size_t)node * 2 + pos]);
    }
    for (int e = beg + g; e < end; e += 32) {    // 32 edges in flight
        int s = srcs[e];
        float va = a_s2[s];
        uint4 h = h2v[(size_t)s * 2 + pos];
        float v = va + adn; v = fmaxf(v, NEG_SLOPE * v);
        float p = __expf(v - CSHIFT);
        l += p;
        acc8(a, p, h);
    }
    // merge the 32 groups (lane bits 1..5)
#pragma unroll
    for (int off = 2; off < 64; off <<= 1) {
        l += __shfl_xor(l, off);
#pragma unroll
        for (int j = 0; j < 8; ++j) a[j] += __shfl_xor(a[j], off);
    }
    float inv = 1.f / (l + EPS_DEN);
    float4 bb0 = ((const float4*)b2)[pos * 2];
    float4 bb1 = ((const float4*)b2)[pos * 2 + 1];
    float o[8];
    o[0] = fmaf(a[0], inv, bb0.x); o[1] = fmaf(a[1], inv, bb0.y);
    o[2] = fmaf(a[2], inv, bb0.z); o[3] = fmaf(a[3], inv, bb0.w);
    o[4] = fmaf(a[4], inv, bb1.x); o[5] = fmaf(a[5], inv, bb1.y);
    o[6] = fmaf(a[6], inv, bb1.z); o[7] = fmaf(a[7], inv, bb1.w);
    // log_softmax over 16 classes (8 per lane + pair lane via xor 1)
    float mx = o[0];
#pragma unroll
    for (int j = 1; j < 8; ++j) mx = fmaxf(mx, o[j]);
    mx = fmaxf(mx, __shfl_xor(mx, 1));
    float se = 0.f;
#pragma unroll
    for (int j = 0; j < 8; ++j) se += __expf(o[j] - mx);
    se += __shfl_xor(se, 1);
    float ls = mx + logf(se);
    if (g == 0) {
        ((float4*)out)[(size_t)node * 4 + pos * 2] =
            make_float4(o[0] - ls, o[1] - ls, o[2] - ls, o[3] - ls);
        ((float4*)out)[(size_t)node * 4 + pos * 2 + 1] =
            make_float4(o[4] - ls, o[5] - ls, o[6] - ls, o[7] - ls);
    }
}

// ---------------------------------------------------------------------------

extern "C" void kernel_launch(void* const* d_in, const int* in_sizes, int n_in,
                              void* d_out, int out_size, void* d_ws, size_t ws_size,
                              hipStream_t stream) {
    const float* x    = (const float*)d_in[0];
    const int*   ei   = (const int*)d_in[1];
    const float* W1   = (const float*)d_in[2];
    const float* b1   = (const float*)d_in[3];
    const float* as1  = (const float*)d_in[4];
    const float* ad1  = (const float*)d_in[5];
    const float* W2   = (const float*)d_in[6];
    const float* b2   = (const float*)d_in[7];
    const float* as2  = (const float*)d_in[8];
    const float* ad2  = (const float*)d_in[9];
    float* out = (float*)d_out;

    int N = in_sizes[0] / 128;
    int E = in_sizes[1] / 2;
    const int* srcp = ei;
    const int* dstp = ei + E;
    int nbuck = (N + 511) >> 9;               // 196 for N=100k

    char* w = (char*)d_ws;
    auto alloc = [&](size_t bytes) {
        void* p = (void*)w;
        w += (bytes + 255) & ~(size_t)255;
        return p;
    };
    unsigned short* h1b = (unsigned short*)alloc((size_t)N * 64 * 2);
    float* a_s1  = (float*)alloc((size_t)N * 8 * 4);
    float* a_d1  = (float*)alloc((size_t)N * 8 * 4);
    unsigned short* h2b = (unsigned short*)alloc((size_t)N * 16 * 2);
    float* a_s2b = (float*)alloc((size_t)N * 4);
    float* a_d2b = (float*)alloc((size_t)N * 4);
    int*   rowp  = (int*)alloc((size_t)(N + 1) * 4);
    int*   srcs  = (int*)alloc((size_t)E * 4);
    int*   gcur  = (int*)alloc((size_t)nbuck * 4);
    int*   gbase = (int*)alloc((size_t)nbuck * 4);
    int*   buf   = (int*)alloc((size_t)nbuck * BCAP * 4);  // 12.85 MB

    hipMemsetAsync(gcur, 0, (size_t)nbuck * 4, stream);

    int bblk = (E + ECHUNK - 1) / ECHUNK;
    bucket_kernel<<<bblk, 256, 0, stream>>>(srcp, dstp, gcur, buf, E, nbuck);
    gscan_kernel<<<1, 64, 0, stream>>>(gcur, gbase, nbuck);
    csr_bucket_kernel<<<nbuck, 256, 0, stream>>>(gcur, gbase, buf, rowp, srcs, N, E);

    int g1blocks = (N + 63) >> 6;
    gemm1_mfma_kernel<<<g1blocks, 256, 0, stream>>>(x, W1, as1, ad1, h1b, a_s1, a_d1, N);
    agg1_fused_kernel<<<(N + 3) / 4, 256, 0, stream>>>(
        h1b, a_s1, a_d1, rowp, srcs, b1, W2, as2, ad2, h2b, a_s2b, a_d2b, N);
    agg2_kernel<<<(N + 3) / 4, 256, 0, stream>>>(h2b, a_s2b, a_d2b, rowp, srcs, b2, out, N);
}

// Round 10
// 354.422 us; speedup vs baseline: 1.3140x; 1.0049x over previous
//
#include <hip/hip_runtime.h>
#include <hip/hip_bf16.h>

// ---------------------------------------------------------------------------
// 2-layer GAT (PyG GATConv semantics, eval mode, self-loops appended).
//   1) bucket (dst>>9, 196 buckets) -> gscan -> csr_bucket (512-node):
//      CSR build, separate kernels (R8 post-mortem: do NOT fuse the
//      scatter/atomic personality with the MFMA personality in one grid)
//   2) gemm1 (MFMA 16x16x32 bf16): h1 = x @ W1 -> bf16 + a_s/a_d epilogue
//   3) agg1_fused: additive exp(v-8) softmax agg (8 lanes/edge, uint4 bf16
//      gathers, 4-deep unroll = 32 edges in flight — R9 post-mortem: unroll
//      depth IS the latency hiding; 2-deep halved MLP and doubled time)
//      + bias + ELU + fused gemm2 (he@W2) + a_s2/a_d2 -> h2b
//   4) agg2: additive agg, 2 lanes/edge x 32 groups + fused log_softmax
// ---------------------------------------------------------------------------

#define NEG_SLOPE 0.2f
#define EPS_DEN 1e-16f
#define CSHIFT 8.0f          // shift-invariant softmax; |logit| <~ 9 here
#define NBUCK_MAX 256
#define BCAP 16384           // per-512-node-bucket capacity (mean ~8.7k)
#define ECHUNK 2048
#define G1_PITCH 136

typedef __attribute__((ext_vector_type(8))) short bf16x8;
typedef __attribute__((ext_vector_type(4))) float f32x4;

__device__ __forceinline__ float bf2f(unsigned short u) {
    return __uint_as_float(((unsigned)u) << 16);
}
__device__ __forceinline__ unsigned short f2bf(float f) {
    unsigned x = __float_as_uint(f);
    unsigned r = x + 0x7fffu + ((x >> 16) & 1u);
    return (unsigned short)(r >> 16);
}
__device__ __forceinline__ void bf2f2(unsigned u, float& lo, float& hi) {
    lo = __uint_as_float(u << 16);
    hi = __uint_as_float(u & 0xffff0000u);
}
// a[0..7] += p * bf16x8(h)
__device__ __forceinline__ void acc8(float* a, float p, uint4 h) {
    float f0, f1;
    bf2f2(h.x, f0, f1); a[0] = fmaf(p, f0, a[0]); a[1] = fmaf(p, f1, a[1]);
    bf2f2(h.y, f0, f1); a[2] = fmaf(p, f0, a[2]); a[3] = fmaf(p, f1, a[3]);
    bf2f2(h.z, f0, f1); a[4] = fmaf(p, f0, a[4]); a[5] = fmaf(p, f1, a[5]);
    bf2f2(h.w, f0, f1); a[6] = fmaf(p, f0, a[6]); a[7] = fmaf(p, f1, a[7]);
}

// ---------------- CSR build (separate kernels — R7 structure) ----------------

__global__ __launch_bounds__(256) void bucket_kernel(
    const int* __restrict__ src, const int* __restrict__ dst,
    int* __restrict__ gcur, int* __restrict__ buf, int E, int nbuck)
{
    __shared__ int cnt[NBUCK_MAX];
    __shared__ int offs[NBUCK_MAX];
    int tid = threadIdx.x;
    for (int i = tid; i < nbuck; i += 256) cnt[i] = 0;
    __syncthreads();
    int base = blockIdx.x * ECHUNK;
    int lim = min(base + ECHUNK, E);
    for (int e = base + tid; e < lim; e += 256)
        atomicAdd(&cnt[dst[e] >> 9], 1);
    __syncthreads();
    for (int i = tid; i < nbuck; i += 256) {
        offs[i] = atomicAdd(&gcur[i], cnt[i]);
        cnt[i] = 0;
    }
    __syncthreads();
    for (int e = base + tid; e < lim; e += 256) {
        int d = dst[e];
        int b = d >> 9;
        int idx = offs[b] + atomicAdd(&cnt[b], 1);
        if (idx < BCAP)
            buf[(size_t)b * BCAP + idx] = (src[e] << 9) | (d & 511);
    }
}

__global__ void gscan_kernel(const int* __restrict__ gcur, int* __restrict__ gbase, int B) {
    int lane = threadIdx.x;
    int carry = 0;
    for (int base = 0; base < B; base += 64) {
        int i = base + lane;
        int v = (i < B) ? gcur[i] : 0;
        int sc = v;
#pragma unroll
        for (int off = 1; off < 64; off <<= 1) {
            int o = __shfl_up(sc, off);
            if (lane >= off) sc += o;
        }
        if (i < B) gbase[i] = carry + sc - v;
        carry += __shfl(sc, 63);
    }
}

__global__ __launch_bounds__(256) void csr_bucket_kernel(
    const int* __restrict__ gcur, const int* __restrict__ gbase,
    const int* __restrict__ buf, int* __restrict__ rowptr,
    int* __restrict__ srcs, int N, int E)
{
    __shared__ int cnt[512];
    __shared__ int wsum[4];
    __shared__ int wbase[4];
    int b = blockIdx.x, tid = threadIdx.x;
    int lane = tid & 63, wv = tid >> 6;
    cnt[2 * tid] = 0; cnt[2 * tid + 1] = 0;
    __syncthreads();
    int n = min(gcur[b], BCAP);
    const int* p = buf + (size_t)b * BCAP;
    for (int i = tid; i < n; i += 256) atomicAdd(&cnt[p[i] & 511], 1);
    __syncthreads();
    int c0 = cnt[2 * tid], c1 = cnt[2 * tid + 1];
    int s = c0 + c1;
    int sc = s;
#pragma unroll
    for (int off = 1; off < 64; off <<= 1) {
        int o = __shfl_up(sc, off);
        if (lane >= off) sc += o;
    }
    if (lane == 63) wsum[wv] = sc;
    __syncthreads();
    if (tid == 0) {
        int acc = 0;
#pragma unroll
        for (int k = 0; k < 4; ++k) { wbase[k] = acc; acc += wsum[k]; }
    }
    __syncthreads();
    int base = gbase[b];
    int g0 = base + wbase[wv] + (sc - s);
    int g1 = g0 + c0;
    int node0 = (b << 9) + 2 * tid;
    if (node0 < N)     rowptr[node0]     = g0;
    if (node0 + 1 < N) rowptr[node0 + 1] = g1;
    cnt[2 * tid] = g0; cnt[2 * tid + 1] = g1;   // reuse as placement cursors
    __syncthreads();
    for (int i = tid; i < n; i += 256) {
        int v = p[i];
        int posi = atomicAdd(&cnt[v & 511], 1);
        srcs[posi] = v >> 9;
    }
    if (b == 0 && tid == 0) rowptr[N] = E;
}

// ---------------- GEMM1 (MFMA): [N,128] @ [128,64] -> bf16 -------------------

__global__ __launch_bounds__(256) void gemm1_mfma_kernel(
    const float* __restrict__ x, const float* __restrict__ W1,
    const float* __restrict__ att_s, const float* __restrict__ att_d,
    unsigned short* __restrict__ h1b, float* __restrict__ a_s,
    float* __restrict__ a_d, int N)
{
    __shared__ unsigned short As[64 * G1_PITCH];
    __shared__ unsigned short Cs[64 * 68];
    int tid = threadIdx.x;
    int lane = tid & 63, wv = tid >> 6;
    int quad = lane >> 4, l16 = lane & 15;

    bf16x8 Bf[4][4];
#pragma unroll
    for (int ks = 0; ks < 4; ++ks)
#pragma unroll
        for (int nt = 0; nt < 4; ++nt) {
            bf16x8 f;
#pragma unroll
            for (int j = 0; j < 8; ++j)
                f[j] = (short)f2bf(W1[(ks * 32 + quad * 8 + j) * 64 + nt * 16 + l16]);
            Bf[ks][nt] = f;
        }
    float asw[4], adw[4];
#pragma unroll
    for (int nt = 0; nt < 4; ++nt) {
        asw[nt] = att_s[nt * 16 + l16];
        adw[nt] = att_d[nt * 16 + l16];
    }

    int nblocks = (N + 63) >> 6;
    for (int blk = blockIdx.x; blk < nblocks; blk += gridDim.x) {
        int row0 = blk << 6;
        __syncthreads();
#pragma unroll
        for (int i = 0; i < 8; ++i) {
            int idx = tid + 256 * i;
            int r = idx >> 5, c4 = idx & 31;
            int row = row0 + r;
            float4 v = (row < N) ? ((const float4*)x)[(size_t)row * 32 + c4]
                                 : make_float4(0.f, 0.f, 0.f, 0.f);
            ushort4 u;
            u.x = f2bf(v.x); u.y = f2bf(v.y); u.z = f2bf(v.z); u.w = f2bf(v.w);
            *(ushort4*)&As[r * G1_PITCH + c4 * 4] = u;
        }
        __syncthreads();
        f32x4 acc[4];
#pragma unroll
        for (int nt = 0; nt < 4; ++nt) acc[nt] = (f32x4){0.f, 0.f, 0.f, 0.f};
#pragma unroll
        for (int ks = 0; ks < 4; ++ks) {
            bf16x8 Af = *(const bf16x8*)&As[(wv * 16 + l16) * G1_PITCH + ks * 32 + quad * 8];
#pragma unroll
            for (int nt = 0; nt < 4; ++nt)
                acc[nt] = __builtin_amdgcn_mfma_f32_16x16x32_bf16(Af, Bf[ks][nt], acc[nt], 0, 0, 0);
        }
        int lrow = wv * 16 + quad * 4;
#pragma unroll
        for (int nt = 0; nt < 4; ++nt) {
            float ps[4], pd[4];
#pragma unroll
            for (int r = 0; r < 4; ++r) {
                ps[r] = acc[nt][r] * asw[nt];
                pd[r] = acc[nt][r] * adw[nt];
            }
#pragma unroll
            for (int off = 1; off < 8; off <<= 1)
#pragma unroll
                for (int r = 0; r < 4; ++r) {
                    ps[r] += __shfl_xor(ps[r], off);
                    pd[r] += __shfl_xor(pd[r], off);
                }
            if ((l16 & 7) == 0) {
                int head = nt * 2 + (l16 >> 3);
#pragma unroll
                for (int r = 0; r < 4; ++r) {
                    int row = row0 + lrow + r;
                    if (row < N) {
                        a_s[row * 8 + head] = ps[r];
                        a_d[row * 8 + head] = pd[r];
                    }
                }
            }
        }
#pragma unroll
        for (int nt = 0; nt < 4; ++nt)
#pragma unroll
            for (int r = 0; r < 4; ++r)
                Cs[(lrow + r) * 68 + nt * 16 + l16] = f2bf(acc[nt][r]);
        __syncthreads();
#pragma unroll
        for (int i = 0; i < 4; ++i) {
            int idx = tid + 256 * i;
            int r = idx >> 4, c4 = idx & 15;
            int row = row0 + r;
            if (row < N) {
                ushort4 u = *(const ushort4*)&Cs[r * 68 + c4 * 4];
                ((ushort4*)h1b)[(size_t)row * 16 + c4] = u;
            }
        }
    }
}

// ---------------- agg1 fused: softmax agg + ELU + gemm2 + a_s2/a_d2 ----------
// g=lane>>3 edge-group, pos=lane&7 = head; 8 channels (uint4 bf16) per lane.
// 4-deep unroll per group: 32 edges in flight, 12 loads/lane outstanding.

__global__ __launch_bounds__(256) void agg1_fused_kernel(
    const unsigned short* __restrict__ h1b, const float* __restrict__ a_s,
    const float* __restrict__ a_d, const int* __restrict__ rowptr,
    const int* __restrict__ srcs, const float* __restrict__ b1,
    const float* __restrict__ W2, const float* __restrict__ att_s2,
    const float* __restrict__ att_d2, unsigned short* __restrict__ h2b,
    float* __restrict__ a_s2, float* __restrict__ a_d2, int N)
{
    int lane = threadIdx.x & 63, wid = threadIdx.x >> 6;
    int node = blockIdx.x * 4 + wid;
    if (node >= N) return;
    int g = lane >> 3, pos = lane & 7;
    int beg = rowptr[node], end = rowptr[node + 1];
    float adn = a_d[node * 8 + pos];
    const uint4* h1v = (const uint4*)h1b;        // 8 uint4 per 64-ch row

    float l = 0.f, a[8] = {0.f, 0.f, 0.f, 0.f, 0.f, 0.f, 0.f, 0.f};
    if (g == 0) {                                // self-loop in group 0
        float v = a_s[node * 8 + pos] + adn;
        v = fmaxf(v, NEG_SLOPE * v);
        float p = __expf(v - CSHIFT);
        l = p;
        acc8(a, p, h1v[(size_t)node * 8 + pos]);
    }
    int e = beg + g;
    for (; e + 24 < end; e += 32) {              // 4-deep, 32 edges in flight
        int s0 = srcs[e],      s1 = srcs[e + 8];
        int s2 = srcs[e + 16], s3 = srcs[e + 24];
        float va0 = a_s[s0 * 8 + pos], va1 = a_s[s1 * 8 + pos];
        float va2 = a_s[s2 * 8 + pos], va3 = a_s[s3 * 8 + pos];
        uint4 h0 = h1v[(size_t)s0 * 8 + pos];
        uint4 h1_ = h1v[(size_t)s1 * 8 + pos];
        uint4 h2_ = h1v[(size_t)s2 * 8 + pos];
        uint4 h3_ = h1v[(size_t)s3 * 8 + pos];
        float v0 = va0 + adn; v0 = fmaxf(v0, NEG_SLOPE * v0);
        float v1 = va1 + adn; v1 = fmaxf(v1, NEG_SLOPE * v1);
        float v2 = va2 + adn; v2 = fmaxf(v2, NEG_SLOPE * v2);
        float v3 = va3 + adn; v3 = fmaxf(v3, NEG_SLOPE * v3);
        float p0 = __expf(v0 - CSHIFT), p1 = __expf(v1 - CSHIFT);
        float p2 = __expf(v2 - CSHIFT), p3 = __expf(v3 - CSHIFT);
        l += p0 + p1 + p2 + p3;
        acc8(a, p0, h0);
        acc8(a, p1, h1_);
        acc8(a, p2, h2_);
        acc8(a, p3, h3_);
    }
    for (; e < end; e += 8) {
        int s = srcs[e];
        float va = a_s[s * 8 + pos];
        uint4 h = h1v[(size_t)s * 8 + pos];
        float v = va + adn; v = fmaxf(v, NEG_SLOPE * v);
        float p = __expf(v - CSHIFT);
        l += p;
        acc8(a, p, h);
    }
    // merge the 8 groups (plain sums; lane bits 3..5)
#pragma unroll
    for (int off = 8; off < 64; off <<= 1) {
        l += __shfl_xor(l, off);
#pragma unroll
        for (int j = 0; j < 8; ++j) a[j] += __shfl_xor(a[j], off);
    }
    float inv = 1.f / (l + EPS_DEN);
    float4 bb0 = ((const float4*)b1)[pos * 2];
    float4 bb1 = ((const float4*)b1)[pos * 2 + 1];
    float o[8];
    o[0] = fmaf(a[0], inv, bb0.x); o[1] = fmaf(a[1], inv, bb0.y);
    o[2] = fmaf(a[2], inv, bb0.z); o[3] = fmaf(a[3], inv, bb0.w);
    o[4] = fmaf(a[4], inv, bb1.x); o[5] = fmaf(a[5], inv, bb1.y);
    o[6] = fmaf(a[6], inv, bb1.z); o[7] = fmaf(a[7], inv, bb1.w);
#pragma unroll
    for (int j = 0; j < 8; ++j)
        o[j] = o[j] > 0.f ? o[j] : __expf(o[j]) - 1.f;   // ELU -> he (regs)

    // fused gemm2: group g computes classes 2g, 2g+1
    float r0 = 0.f, r1 = 0.f;
#pragma unroll
    for (int j = 0; j < 8; ++j) {
        float2 w = ((const float2*)W2)[(8 * pos + j) * 8 + g];
        r0 = fmaf(o[j], w.x, r0);
        r1 = fmaf(o[j], w.y, r1);
    }
    // sum over k (pos dimension: lane bits 0..2)
    r0 += __shfl_xor(r0, 1); r1 += __shfl_xor(r1, 1);
    r0 += __shfl_xor(r0, 2); r1 += __shfl_xor(r1, 2);
    r0 += __shfl_xor(r0, 4); r1 += __shfl_xor(r1, 4);
    // a_s2/a_d2 = sum_c h2[c]*att2[c] (partials per group, reduce over g)
    float2 ws = ((const float2*)att_s2)[g];
    float2 wd = ((const float2*)att_d2)[g];
    float ps = r0 * ws.x + r1 * ws.y;
    float pd = r0 * wd.x + r1 * wd.y;
    ps += __shfl_xor(ps, 8);  pd += __shfl_xor(pd, 8);
    ps += __shfl_xor(ps, 16); pd += __shfl_xor(pd, 16);
    ps += __shfl_xor(ps, 32); pd += __shfl_xor(pd, 32);
    if (pos == 0) {
        ushort2 u; u.x = f2bf(r0); u.y = f2bf(r1);
        ((ushort2*)h2b)[(size_t)node * 8 + g] = u;
    }
    if (lane == 0) { a_s2[node] = ps; a_d2[node] = pd; }
}

// ---------------- agg2: 2 lanes/edge x 32 groups + fused log_softmax ---------

__global__ __launch_bounds__(256) void agg2_kernel(
    const unsigned short* __restrict__ h2b, const float* __restrict__ a_s2,
    const float* __restrict__ a_d2, const int* __restrict__ rowptr,
    const int* __restrict__ srcs, const float* __restrict__ b2,
    float* __restrict__ out, int N)
{
    int lane = threadIdx.x & 63, wid = threadIdx.x >> 6;
    int node = blockIdx.x * 4 + wid;
    if (node >= N) return;
    int g = lane >> 1, pos = lane & 1;
    int beg = rowptr[node], end = rowptr[node + 1];
    float adn = a_d2[node];
    const uint4* h2v = (const uint4*)h2b;        // 2 uint4 per 16-ch row

    float l = 0.f, a[8] = {0.f, 0.f, 0.f, 0.f, 0.f, 0.f, 0.f, 0.f};
    if (g == 0) {                                // self-loop in group 0
        float v = a_s2[node] + adn;
        v = fmaxf(v, NEG_SLOPE * v);
        float p = __expf(v - CSHIFT);
        l = p;
        acc8(a, p, h2v[(size_t)node * 2 + pos]);
    }
    for (int e = beg + g; e < end; e += 32) {    // 32 edges in flight
        int s = srcs[e];
        float va = a_s2[s];
        uint4 h = h2v[(size_t)s * 2 + pos];
        float v = va + adn; v = fmaxf(v, NEG_SLOPE * v);
        float p = __expf(v - CSHIFT);
        l += p;
        acc8(a, p, h);
    }
    // merge the 32 groups (lane bits 1..5)
#pragma unroll
    for (int off = 2; off < 64; off <<= 1) {
        l += __shfl_xor(l, off);
#pragma unroll
        for (int j = 0; j < 8; ++j) a[j] += __shfl_xor(a[j], off);
    }
    float inv = 1.f / (l + EPS_DEN);
    float4 bb0 = ((const float4*)b2)[pos * 2];
    float4 bb1 = ((const float4*)b2)[pos * 2 + 1];
    float o[8];
    o[0] = fmaf(a[0], inv, bb0.x); o[1] = fmaf(a[1], inv, bb0.y);
    o[2] = fmaf(a[2], inv, bb0.z); o[3] = fmaf(a[3], inv, bb0.w);
    o[4] = fmaf(a[4], inv, bb1.x); o[5] = fmaf(a[5], inv, bb1.y);
    o[6] = fmaf(a[6], inv, bb1.z); o[7] = fmaf(a[7], inv, bb1.w);
    // log_softmax over 16 classes (8 per lane + pair lane via xor 1)
    float mx = o[0];
#pragma unroll
    for (int j = 1; j < 8; ++j) mx = fmaxf(mx, o[j]);
    mx = fmaxf(mx, __shfl_xor(mx, 1));
    float se = 0.f;
#pragma unroll
    for (int j = 0; j < 8; ++j) se += __expf(o[j] - mx);
    se += __shfl_xor(se, 1);
    float ls = mx + logf(se);
    if (g == 0) {
        ((float4*)out)[(size_t)node * 4 + pos * 2] =
            make_float4(o[0] - ls, o[1] - ls, o[2] - ls, o[3] - ls);
        ((float4*)out)[(size_t)node * 4 + pos * 2 + 1] =
            make_float4(o[4] - ls, o[5] - ls, o[6] - ls, o[7] - ls);
    }
}

// ---------------------------------------------------------------------------

extern "C" void kernel_launch(void* const* d_in, const int* in_sizes, int n_in,
                              void* d_out, int out_size, void* d_ws, size_t ws_size,
                              hipStream_t stream) {
    const float* x    = (const float*)d_in[0];
    const int*   ei   = (const int*)d_in[1];
    const float* W1   = (const float*)d_in[2];
    const float* b1   = (const float*)d_in[3];
    const float* as1  = (const float*)d_in[4];
    const float* ad1  = (const float*)d_in[5];
    const float* W2   = (const float*)d_in[6];
    const float* b2   = (const float*)d_in[7];
    const float* as2  = (const float*)d_in[8];
    const float* ad2  = (const float*)d_in[9];
    float* out = (float*)d_out;

    int N = in_sizes[0] / 128;
    int E = in_sizes[1] / 2;
    const int* srcp = ei;
    const int* dstp = ei + E;
    int nbuck = (N + 511) >> 9;               // 196 for N=100k

    char* w = (char*)d_ws;
    auto alloc = [&](size_t bytes) {
        void* p = (void*)w;
        w += (bytes + 255) & ~(size_t)255;
        return p;
    };
    unsigned short* h1b = (unsigned short*)alloc((size_t)N * 64 * 2);
    float* a_s1  = (float*)alloc((size_t)N * 8 * 4);
    float* a_d1  = (float*)alloc((size_t)N * 8 * 4);
    unsigned short* h2b = (unsigned short*)alloc((size_t)N * 16 * 2);
    float* a_s2b = (float*)alloc((size_t)N * 4);
    float* a_d2b = (float*)alloc((size_t)N * 4);
    int*   rowp  = (int*)alloc((size_t)(N + 1) * 4);
    int*   srcs  = (int*)alloc((size_t)E * 4);
    int*   gcur  = (int*)alloc((size_t)nbuck * 4);
    int*   gbase = (int*)alloc((size_t)nbuck * 4);
    int*   buf   = (int*)alloc((size_t)nbuck * BCAP * 4);  // 12.85 MB

    hipMemsetAsync(gcur, 0, (size_t)nbuck * 4, stream);

    int bblk = (E + ECHUNK - 1) / ECHUNK;
    bucket_kernel<<<bblk, 256, 0, stream>>>(srcp, dstp, gcur, buf, E, nbuck);
    gscan_kernel<<<1, 64, 0, stream>>>(gcur, gbase, nbuck);
    csr_bucket_kernel<<<nbuck, 256, 0, stream>>>(gcur, gbase, buf, rowp, srcs, N, E);

    int g1blocks = (N + 63) >> 6;
    gemm1_mfma_kernel<<<g1blocks, 256, 0, stream>>>(x, W1, as1, ad1, h1b, a_s1, a_d1, N);
    agg1_fused_kernel<<<(N + 3) / 4, 256, 0, stream>>>(
        h1b, a_s1, a_d1, rowp, srcs, b1, W2, as2, ad2, h2b, a_s2b, a_d2b, N);
    agg2_kernel<<<(N + 3) / 4, 256, 0, stream>>>(h2b, a_s2b, a_d2b, rowp, srcs, b2, out, N);
}

// Round 11
// 296.103 us; speedup vs baseline: 1.5728x; 1.1970x over previous
//
#include <hip/hip_runtime.h>
#include <hip/hip_bf16.h>

// ---------------------------------------------------------------------------
// 2-layer GAT (PyG GATConv semantics, eval mode, self-loops appended).
// R10 post-mortem: agg1 must keep per-lane staging <= 8 B (ushort4): with
// 16 B uint4 staging the compiler's occupancy-targeted VGPR budget (32)
// recycles staging regs and serializes the gathers. This file = exact R7
// composite (297 us) + register-staged bucket_kernel reads.
//   1) bucket (dst>>9) -> gscan -> csr_bucket (512-node buckets)
//   2) gemm1 (MFMA 16x16x32 bf16): h1 = x @ W1 -> bf16 + a_s/a_d epilogue
//   3) agg1: additive exp(v-8) agg, 16 lanes/edge ushort4, 4 groups x 4-deep
//   4) gemm2: he @ W2 -> bf16 + a_s2/a_d2 epilogue
//   5) agg2: additive agg, 4 lanes/edge ushort4, 16 groups x 2-deep
//      + fused log_softmax
// ---------------------------------------------------------------------------

#define NEG_SLOPE 0.2f
#define EPS_DEN 1e-16f
#define CSHIFT 8.0f          // shift-invariant softmax; |logit| <~ 9 here
#define NBUCK_MAX 256
#define BCAP 16384
#define ECHUNK 2048
#define G1_PITCH 136

typedef __attribute__((ext_vector_type(8))) short bf16x8;
typedef __attribute__((ext_vector_type(4))) float f32x4;

__device__ __forceinline__ float bf2f(unsigned short u) {
    return __uint_as_float(((unsigned)u) << 16);
}
__device__ __forceinline__ unsigned short f2bf(float f) {
    unsigned x = __float_as_uint(f);
    unsigned r = x + 0x7fffu + ((x >> 16) & 1u);
    return (unsigned short)(r >> 16);
}

// ---------------- CSR build ----------------

__global__ __launch_bounds__(256) void bucket_kernel(
    const int* __restrict__ src, const int* __restrict__ dst,
    int* __restrict__ gcur, int* __restrict__ buf, int E, int nbuck)
{
    __shared__ int cnt[NBUCK_MAX];
    __shared__ int offs[NBUCK_MAX];
    int tid = threadIdx.x;
    for (int i = tid; i < nbuck; i += 256) cnt[i] = 0;
    __syncthreads();
    int base = blockIdx.x * ECHUNK;
    int lim = min(base + ECHUNK, E);
    int dl[8];                                  // ECHUNK == 256*8
#pragma unroll
    for (int k = 0; k < 8; ++k) {
        int e = base + tid + 256 * k;
        dl[k] = (e < lim) ? dst[e] : -1;
    }
#pragma unroll
    for (int k = 0; k < 8; ++k)
        if (dl[k] >= 0) atomicAdd(&cnt[dl[k] >> 9], 1);
    __syncthreads();
    for (int i = tid; i < nbuck; i += 256) {
        offs[i] = atomicAdd(&gcur[i], cnt[i]);
        cnt[i] = 0;
    }
    __syncthreads();
#pragma unroll
    for (int k = 0; k < 8; ++k) {
        if (dl[k] >= 0) {
            int e = base + tid + 256 * k;
            int b = dl[k] >> 9;
            int idx = offs[b] + atomicAdd(&cnt[b], 1);
            if (idx < BCAP)
                buf[(size_t)b * BCAP + idx] = (src[e] << 9) | (dl[k] & 511);
        }
    }
}

__global__ void gscan_kernel(const int* __restrict__ gcur, int* __restrict__ gbase, int B) {
    int lane = threadIdx.x;
    int carry = 0;
    for (int base = 0; base < B; base += 64) {
        int i = base + lane;
        int v = (i < B) ? gcur[i] : 0;
        int sc = v;
#pragma unroll
        for (int off = 1; off < 64; off <<= 1) {
            int o = __shfl_up(sc, off);
            if (lane >= off) sc += o;
        }
        if (i < B) gbase[i] = carry + sc - v;
        carry += __shfl(sc, 63);
    }
}

__global__ __launch_bounds__(256) void csr_bucket_kernel(
    const int* __restrict__ gcur, const int* __restrict__ gbase,
    const int* __restrict__ buf, int* __restrict__ rowptr,
    int* __restrict__ srcs, int N, int E)
{
    __shared__ int cnt[512];
    __shared__ int wsum[4];
    __shared__ int wbase[4];
    int b = blockIdx.x, tid = threadIdx.x;
    int lane = tid & 63, wv = tid >> 6;
    cnt[2 * tid] = 0; cnt[2 * tid + 1] = 0;
    __syncthreads();
    int n = min(gcur[b], BCAP);
    const int* p = buf + (size_t)b * BCAP;
    for (int i = tid; i < n; i += 256) atomicAdd(&cnt[p[i] & 511], 1);
    __syncthreads();
    int c0 = cnt[2 * tid], c1 = cnt[2 * tid + 1];
    int s = c0 + c1;
    int sc = s;
#pragma unroll
    for (int off = 1; off < 64; off <<= 1) {
        int o = __shfl_up(sc, off);
        if (lane >= off) sc += o;
    }
    if (lane == 63) wsum[wv] = sc;
    __syncthreads();
    if (tid == 0) {
        int acc = 0;
#pragma unroll
        for (int k = 0; k < 4; ++k) { wbase[k] = acc; acc += wsum[k]; }
    }
    __syncthreads();
    int base = gbase[b];
    int g0 = base + wbase[wv] + (sc - s);
    int g1 = g0 + c0;
    int node0 = (b << 9) + 2 * tid;
    if (node0 < N)     rowptr[node0]     = g0;
    if (node0 + 1 < N) rowptr[node0 + 1] = g1;
    cnt[2 * tid] = g0; cnt[2 * tid + 1] = g1;   // reuse as placement cursors
    __syncthreads();
    for (int i = tid; i < n; i += 256) {
        int v = p[i];
        int posi = atomicAdd(&cnt[v & 511], 1);
        srcs[posi] = v >> 9;
    }
    if (b == 0 && tid == 0) rowptr[N] = E;
}

// ---------------- GEMM1 (MFMA): [N,128] @ [128,64] -> bf16 -------------------

__global__ __launch_bounds__(256) void gemm1_mfma_kernel(
    const float* __restrict__ x, const float* __restrict__ W1,
    const float* __restrict__ att_s, const float* __restrict__ att_d,
    unsigned short* __restrict__ h1b, float* __restrict__ a_s,
    float* __restrict__ a_d, int N)
{
    __shared__ unsigned short As[64 * G1_PITCH];
    __shared__ unsigned short Cs[64 * 68];
    int tid = threadIdx.x;
    int lane = tid & 63, wv = tid >> 6;
    int quad = lane >> 4, l16 = lane & 15;

    bf16x8 Bf[4][4];
#pragma unroll
    for (int ks = 0; ks < 4; ++ks)
#pragma unroll
        for (int nt = 0; nt < 4; ++nt) {
            bf16x8 f;
#pragma unroll
            for (int j = 0; j < 8; ++j)
                f[j] = (short)f2bf(W1[(ks * 32 + quad * 8 + j) * 64 + nt * 16 + l16]);
            Bf[ks][nt] = f;
        }
    float asw[4], adw[4];
#pragma unroll
    for (int nt = 0; nt < 4; ++nt) {
        asw[nt] = att_s[nt * 16 + l16];
        adw[nt] = att_d[nt * 16 + l16];
    }

    int nblocks = (N + 63) >> 6;
    for (int blk = blockIdx.x; blk < nblocks; blk += gridDim.x) {
        int row0 = blk << 6;
        __syncthreads();
#pragma unroll
        for (int i = 0; i < 8; ++i) {
            int idx = tid + 256 * i;
            int r = idx >> 5, c4 = idx & 31;
            int row = row0 + r;
            float4 v = (row < N) ? ((const float4*)x)[(size_t)row * 32 + c4]
                                 : make_float4(0.f, 0.f, 0.f, 0.f);
            ushort4 u;
            u.x = f2bf(v.x); u.y = f2bf(v.y); u.z = f2bf(v.z); u.w = f2bf(v.w);
            *(ushort4*)&As[r * G1_PITCH + c4 * 4] = u;
        }
        __syncthreads();
        f32x4 acc[4];
#pragma unroll
        for (int nt = 0; nt < 4; ++nt) acc[nt] = (f32x4){0.f, 0.f, 0.f, 0.f};
#pragma unroll
        for (int ks = 0; ks < 4; ++ks) {
            bf16x8 Af = *(const bf16x8*)&As[(wv * 16 + l16) * G1_PITCH + ks * 32 + quad * 8];
#pragma unroll
            for (int nt = 0; nt < 4; ++nt)
                acc[nt] = __builtin_amdgcn_mfma_f32_16x16x32_bf16(Af, Bf[ks][nt], acc[nt], 0, 0, 0);
        }
        int lrow = wv * 16 + quad * 4;
#pragma unroll
        for (int nt = 0; nt < 4; ++nt) {
            float ps[4], pd[4];
#pragma unroll
            for (int r = 0; r < 4; ++r) {
                ps[r] = acc[nt][r] * asw[nt];
                pd[r] = acc[nt][r] * adw[nt];
            }
#pragma unroll
            for (int off = 1; off < 8; off <<= 1)
#pragma unroll
                for (int r = 0; r < 4; ++r) {
                    ps[r] += __shfl_xor(ps[r], off);
                    pd[r] += __shfl_xor(pd[r], off);
                }
            if ((l16 & 7) == 0) {
                int head = nt * 2 + (l16 >> 3);
#pragma unroll
                for (int r = 0; r < 4; ++r) {
                    int row = row0 + lrow + r;
                    if (row < N) {
                        a_s[row * 8 + head] = ps[r];
                        a_d[row * 8 + head] = pd[r];
                    }
                }
            }
        }
#pragma unroll
        for (int nt = 0; nt < 4; ++nt)
#pragma unroll
            for (int r = 0; r < 4; ++r)
                Cs[(lrow + r) * 68 + nt * 16 + l16] = f2bf(acc[nt][r]);
        __syncthreads();
#pragma unroll
        for (int i = 0; i < 4; ++i) {
            int idx = tid + 256 * i;
            int r = idx >> 4, c4 = idx & 15;
            int row = row0 + r;
            if (row < N) {
                ushort4 u = *(const ushort4*)&Cs[r * 68 + c4 * 4];
                ((ushort4*)h1b)[(size_t)row * 16 + c4] = u;
            }
        }
    }
}

// ---------------- agg1: additive exp(v-8) agg, 16 edges in flight ------------
// q=lane>>4 edge-group (stride 4), pos=lane&15 -> channels 4pos..4pos+3,
// head hp=pos>>1. 8 B/lane staging keeps VGPR pressure low (R10 lesson).

__global__ __launch_bounds__(256) void agg1_kernel(
    const unsigned short* __restrict__ h1b, const float* __restrict__ a_s,
    const float* __restrict__ a_d, const int* __restrict__ rowptr,
    const int* __restrict__ srcs, const float* __restrict__ b1,
    unsigned short* __restrict__ heb, int N)
{
    int lane = threadIdx.x & 63, wid = threadIdx.x >> 6;
    int node = blockIdx.x * 4 + wid;
    if (node >= N) return;
    int q = lane >> 4, pos = lane & 15, hp = pos >> 1;
    int beg = rowptr[node], end = rowptr[node + 1];
    float adn = a_d[node * 8 + hp];
    const ushort4* h1v = (const ushort4*)h1b;    // row stride 16 ushort4

    float l = 0.f, a0 = 0.f, a1 = 0.f, a2 = 0.f, a3 = 0.f;
    if (q == 0) {                                // self-loop in group 0
        float v = a_s[node * 8 + hp] + adn;
        v = fmaxf(v, NEG_SLOPE * v);
        float p = __expf(v - CSHIFT);
        ushort4 h = h1v[(size_t)node * 16 + pos];
        l = p;
        a0 = p * bf2f(h.x); a1 = p * bf2f(h.y);
        a2 = p * bf2f(h.z); a3 = p * bf2f(h.w);
    }
    int e = beg + q;
    for (; e + 12 < end; e += 16) {
        int s0 = srcs[e], s1 = srcs[e + 4], s2 = srcs[e + 8], s3 = srcs[e + 12];
        float va0 = a_s[s0 * 8 + hp], va1 = a_s[s1 * 8 + hp];
        float va2 = a_s[s2 * 8 + hp], va3 = a_s[s3 * 8 + hp];
        ushort4 h0 = h1v[(size_t)s0 * 16 + pos];
        ushort4 h1_ = h1v[(size_t)s1 * 16 + pos];
        ushort4 h2_ = h1v[(size_t)s2 * 16 + pos];
        ushort4 h3_ = h1v[(size_t)s3 * 16 + pos];
        float v0 = va0 + adn; v0 = fmaxf(v0, NEG_SLOPE * v0);
        float v1 = va1 + adn; v1 = fmaxf(v1, NEG_SLOPE * v1);
        float v2 = va2 + adn; v2 = fmaxf(v2, NEG_SLOPE * v2);
        float v3 = va3 + adn; v3 = fmaxf(v3, NEG_SLOPE * v3);
        float p0 = __expf(v0 - CSHIFT), p1 = __expf(v1 - CSHIFT);
        float p2 = __expf(v2 - CSHIFT), p3 = __expf(v3 - CSHIFT);
        l += p0 + p1 + p2 + p3;
        a0 = fmaf(p0, bf2f(h0.x), a0); a1 = fmaf(p0, bf2f(h0.y), a1);
        a2 = fmaf(p0, bf2f(h0.z), a2); a3 = fmaf(p0, bf2f(h0.w), a3);
        a0 = fmaf(p1, bf2f(h1_.x), a0); a1 = fmaf(p1, bf2f(h1_.y), a1);
        a2 = fmaf(p1, bf2f(h1_.z), a2); a3 = fmaf(p1, bf2f(h1_.w), a3);
        a0 = fmaf(p2, bf2f(h2_.x), a0); a1 = fmaf(p2, bf2f(h2_.y), a1);
        a2 = fmaf(p2, bf2f(h2_.z), a2); a3 = fmaf(p2, bf2f(h2_.w), a3);
        a0 = fmaf(p3, bf2f(h3_.x), a0); a1 = fmaf(p3, bf2f(h3_.y), a1);
        a2 = fmaf(p3, bf2f(h3_.z), a2); a3 = fmaf(p3, bf2f(h3_.w), a3);
    }
    for (; e < end; e += 4) {
        int s = srcs[e];
        float va = a_s[s * 8 + hp];
        ushort4 h = h1v[(size_t)s * 16 + pos];
        float v = va + adn; v = fmaxf(v, NEG_SLOPE * v);
        float p = __expf(v - CSHIFT);
        l += p;
        a0 = fmaf(p, bf2f(h.x), a0); a1 = fmaf(p, bf2f(h.y), a1);
        a2 = fmaf(p, bf2f(h.z), a2); a3 = fmaf(p, bf2f(h.w), a3);
    }
#pragma unroll
    for (int off = 16; off < 64; off <<= 1) {
        l  += __shfl_xor(l, off);
        a0 += __shfl_xor(a0, off); a1 += __shfl_xor(a1, off);
        a2 += __shfl_xor(a2, off); a3 += __shfl_xor(a3, off);
    }
    if (q == 0) {
        float inv = 1.f / (l + EPS_DEN);
        float4 bb = ((const float4*)b1)[pos];
        float o0 = fmaf(a0, inv, bb.x);
        float o1 = fmaf(a1, inv, bb.y);
        float o2 = fmaf(a2, inv, bb.z);
        float o3 = fmaf(a3, inv, bb.w);
        o0 = o0 > 0.f ? o0 : __expf(o0) - 1.f;   // ELU
        o1 = o1 > 0.f ? o1 : __expf(o1) - 1.f;
        o2 = o2 > 0.f ? o2 : __expf(o2) - 1.f;
        o3 = o3 > 0.f ? o3 : __expf(o3) - 1.f;
        ushort4 u;
        u.x = f2bf(o0); u.y = f2bf(o1); u.z = f2bf(o2); u.w = f2bf(o3);
        ((ushort4*)heb)[(size_t)node * 16 + pos] = u;
    }
}

// ---------------- GEMM2: [N,64] @ [64,16] -> bf16 + a_s2/a_d2 epilogue -------

__global__ __launch_bounds__(256) void gemm2_kernel(
    const unsigned short* __restrict__ heb, const float* __restrict__ W2,
    const float* __restrict__ att_s2, const float* __restrict__ att_d2,
    unsigned short* __restrict__ h2b, float* __restrict__ a_s2,
    float* __restrict__ a_d2, int N)
{
    __shared__ float xs[4][4 * 68];
    int lane = threadIdx.x & 63, wid = threadIdx.x >> 6;
    int sub = lane >> 4, c = lane & 15;
    float wcol[64];
#pragma unroll
    for (int k = 0; k < 64; ++k) wcol[k] = W2[k * 16 + c];
    float asw = att_s2[c], adw = att_d2[c];
    int groups = (N + 15) >> 4;
    int iters = (groups + gridDim.x - 1) / gridDim.x;
    for (int it = 0; it < iters; ++it) {
        int g = blockIdx.x + it * gridDim.x;
        int nb = g * 16 + wid * 4;
        __syncthreads();
        if (g < groups) {
#pragma unroll
            for (int i = 0; i < 4; ++i) {
                int n = nb + i;
                xs[wid][i * 68 + lane] = (n < N) ? bf2f(heb[(size_t)n * 64 + lane]) : 0.f;
            }
        }
        __syncthreads();
        if (g < groups) {
            int node = nb + sub;
            const float4* xv = (const float4*)&xs[wid][sub * 68];
            float acc = 0.f;
#pragma unroll
            for (int k4 = 0; k4 < 16; ++k4) {
                float4 v = xv[k4];
                acc += v.x * wcol[4 * k4 + 0] + v.y * wcol[4 * k4 + 1]
                     + v.z * wcol[4 * k4 + 2] + v.w * wcol[4 * k4 + 3];
            }
            if (node < N) {
                h2b[(size_t)node * 16 + c] = f2bf(acc);
                float rs = acc * asw, rd = acc * adw;
#pragma unroll
                for (int off = 1; off < 16; off <<= 1) {
                    rs += __shfl_xor(rs, off);
                    rd += __shfl_xor(rd, off);
                }
                if (c == 0) { a_s2[node] = rs; a_d2[node] = rd; }
            }
        }
    }
}

// ---------------- agg2: additive exp(v-8) agg + fused log_softmax ------------
// q=lane>>2 edge-group (stride 16), pos=lane&3 -> classes 4pos..4pos+3.

__global__ __launch_bounds__(256) void agg2_kernel(
    const unsigned short* __restrict__ h2b, const float* __restrict__ a_s2,
    const float* __restrict__ a_d2, const int* __restrict__ rowptr,
    const int* __restrict__ srcs, const float* __restrict__ b2,
    float* __restrict__ out, int N)
{
    int lane = threadIdx.x & 63, wid = threadIdx.x >> 6;
    int node = blockIdx.x * 4 + wid;
    if (node >= N) return;
    int q = lane >> 2, pos = lane & 3;
    int beg = rowptr[node], end = rowptr[node + 1];
    float adn = a_d2[node];
    const ushort4* h2v = (const ushort4*)h2b;    // row stride 4 ushort4

    float l = 0.f, a0 = 0.f, a1 = 0.f, a2 = 0.f, a3 = 0.f;
    if (q == 0) {                                // self-loop in group 0
        float v = a_s2[node] + adn;
        v = fmaxf(v, NEG_SLOPE * v);
        float p = __expf(v - CSHIFT);
        ushort4 h = h2v[(size_t)node * 4 + pos];
        l = p;
        a0 = p * bf2f(h.x); a1 = p * bf2f(h.y);
        a2 = p * bf2f(h.z); a3 = p * bf2f(h.w);
    }
    int e = beg + q;
    for (; e + 16 < end; e += 32) {
        int s0 = srcs[e], s1 = srcs[e + 16];
        float va0 = a_s2[s0], va1 = a_s2[s1];
        ushort4 h0 = h2v[(size_t)s0 * 4 + pos];
        ushort4 h1_ = h2v[(size_t)s1 * 4 + pos];
        float v0 = va0 + adn; v0 = fmaxf(v0, NEG_SLOPE * v0);
        float v1 = va1 + adn; v1 = fmaxf(v1, NEG_SLOPE * v1);
        float p0 = __expf(v0 - CSHIFT), p1 = __expf(v1 - CSHIFT);
        l += p0 + p1;
        a0 = fmaf(p0, bf2f(h0.x), a0); a1 = fmaf(p0, bf2f(h0.y), a1);
        a2 = fmaf(p0, bf2f(h0.z), a2); a3 = fmaf(p0, bf2f(h0.w), a3);
        a0 = fmaf(p1, bf2f(h1_.x), a0); a1 = fmaf(p1, bf2f(h1_.y), a1);
        a2 = fmaf(p1, bf2f(h1_.z), a2); a3 = fmaf(p1, bf2f(h1_.w), a3);
    }
    for (; e < end; e += 16) {
        int s = srcs[e];
        float va = a_s2[s];
        ushort4 h = h2v[(size_t)s * 4 + pos];
        float v = va + adn; v = fmaxf(v, NEG_SLOPE * v);
        float p = __expf(v - CSHIFT);
        l += p;
        a0 = fmaf(p, bf2f(h.x), a0); a1 = fmaf(p, bf2f(h.y), a1);
        a2 = fmaf(p, bf2f(h.z), a2); a3 = fmaf(p, bf2f(h.w), a3);
    }
#pragma unroll
    for (int off = 4; off < 64; off <<= 1) {
        l  += __shfl_xor(l, off);
        a0 += __shfl_xor(a0, off); a1 += __shfl_xor(a1, off);
        a2 += __shfl_xor(a2, off); a3 += __shfl_xor(a3, off);
    }
    if (q == 0) {
        float inv = 1.f / (l + EPS_DEN);
        float4 bb = ((const float4*)b2)[pos];
        float o0 = fmaf(a0, inv, bb.x);
        float o1 = fmaf(a1, inv, bb.y);
        float o2 = fmaf(a2, inv, bb.z);
        float o3 = fmaf(a3, inv, bb.w);
        float mx = fmaxf(fmaxf(o0, o1), fmaxf(o2, o3));
        mx = fmaxf(mx, __shfl_xor(mx, 1));
        mx = fmaxf(mx, __shfl_xor(mx, 2));
        float se = __expf(o0 - mx) + __expf(o1 - mx)
                 + __expf(o2 - mx) + __expf(o3 - mx);
        se += __shfl_xor(se, 1);
        se += __shfl_xor(se, 2);
        float ls = mx + logf(se);
        ((float4*)out)[(size_t)node * 4 + pos] =
            make_float4(o0 - ls, o1 - ls, o2 - ls, o3 - ls);
    }
}

// ---------------------------------------------------------------------------

extern "C" void kernel_launch(void* const* d_in, const int* in_sizes, int n_in,
                              void* d_out, int out_size, void* d_ws, size_t ws_size,
                              hipStream_t stream) {
    const float* x    = (const float*)d_in[0];
    const int*   ei   = (const int*)d_in[1];
    const float* W1   = (const float*)d_in[2];
    const float* b1   = (const float*)d_in[3];
    const float* as1  = (const float*)d_in[4];
    const float* ad1  = (const float*)d_in[5];
    const float* W2   = (const float*)d_in[6];
    const float* b2   = (const float*)d_in[7];
    const float* as2  = (const float*)d_in[8];
    const float* ad2  = (const float*)d_in[9];
    float* out = (float*)d_out;

    int N = in_sizes[0] / 128;
    int E = in_sizes[1] / 2;
    const int* srcp = ei;
    const int* dstp = ei + E;
    int nbuck = (N + 511) >> 9;               // 196 for N=100k

    char* w = (char*)d_ws;
    auto alloc = [&](size_t bytes) {
        void* p = (void*)w;
        w += (bytes + 255) & ~(size_t)255;
        return p;
    };
    unsigned short* h1b = (unsigned short*)alloc((size_t)N * 64 * 2);
    float* a_s1  = (float*)alloc((size_t)N * 8 * 4);
    float* a_d1  = (float*)alloc((size_t)N * 8 * 4);
    unsigned short* heb = (unsigned short*)alloc((size_t)N * 64 * 2);
    unsigned short* h2b = (unsigned short*)alloc((size_t)N * 16 * 2);
    float* a_s2b = (float*)alloc((size_t)N * 4);
    float* a_d2b = (float*)alloc((size_t)N * 4);
    int*   rowp  = (int*)alloc((size_t)(N + 1) * 4);
    int*   srcs  = (int*)alloc((size_t)E * 4);
    int*   gcur  = (int*)alloc((size_t)nbuck * 4);
    int*   gbase = (int*)alloc((size_t)nbuck * 4);
    int*   buf   = (int*)alloc((size_t)nbuck * BCAP * 4);  // 12.85 MB

    hipMemsetAsync(gcur, 0, (size_t)nbuck * 4, stream);

    int bblk = (E + ECHUNK - 1) / ECHUNK;
    bucket_kernel<<<bblk, 256, 0, stream>>>(srcp, dstp, gcur, buf, E, nbuck);
    gscan_kernel<<<1, 64, 0, stream>>>(gcur, gbase, nbuck);
    csr_bucket_kernel<<<nbuck, 256, 0, stream>>>(gcur, gbase, buf, rowp, srcs, N, E);

    int g1blocks = (N + 63) >> 6;
    gemm1_mfma_kernel<<<g1blocks, 256, 0, stream>>>(x, W1, as1, ad1, h1b, a_s1, a_d1, N);
    agg1_kernel<<<(N + 3) / 4, 256, 0, stream>>>(h1b, a_s1, a_d1, rowp, srcs, b1, heb, N);
    gemm2_kernel<<<512, 256, 0, stream>>>(heb, W2, as2, ad2, h2b, a_s2b, a_d2b, N);
    agg2_kernel<<<(N + 3) / 4, 256, 0, stream>>>(h2b, a_s2b, a_d2b, rowp, srcs, b2, out, N);
}